// Round 1
// baseline (106.467 us; speedup 1.0000x reference)
//
#include <hip/hip_runtime.h>
#include <math.h>

#define TEMP_F 0.07f
#define NCON 20
#define LDIM 512
#define NROWS 32768
#define NSEL 16384

// ws layout (floats):
// [0..511]      ebar_sz
// [512..1023]   ebar_nsz
// [1024]        keep-mask sz   (as unsigned bits, bit j set => concept j kept)
// [1025]        keep-mask nsz
// [2048 .. +NROWS)          norm[r]   = ||hg_row r||_2
// [2048+NROWS .. +NROWS)    dot_sz[r] = <hg_row r, ebar_sz>
// [2048+2*NROWS .. +NROWS)  dot_nsz[r]= <hg_row r, ebar_nsz>

__global__ void prep_kernel(const float* __restrict__ all_emb,
                            const int* __restrict__ Psz,
                            const int* __restrict__ Pnsz,
                            float* __restrict__ ws,
                            float* __restrict__ out) {
    int l = threadIdx.x;  // 512 threads
    float ssz = 0.f, snsz = 0.f;
#pragma unroll
    for (int k = 0; k < 5; ++k) {
        ssz  += all_emb[Psz[k]  * LDIM + l];
        snsz += all_emb[Pnsz[k] * LDIM + l];
    }
    ws[l]       = ssz  * 0.2f;   // mean over 5 (duplicates counted, matches ref)
    ws[512 + l] = snsz * 0.2f;
    if (l == 0) {
        unsigned m = (1u << NCON) - 1u;
#pragma unroll
        for (int k = 0; k < 5; ++k) m &= ~(1u << Psz[k]);
        ((unsigned*)ws)[1024] = m;
        unsigned m2 = (1u << NCON) - 1u;
#pragma unroll
        for (int k = 0; k < 5; ++k) m2 &= ~(1u << Pnsz[k]);
        ((unsigned*)ws)[1025] = m2;
        out[0] = 0.f;  // d_out is poisoned before every launch
    }
}

__device__ inline float dot4(float4 a, float4 b) {
    return a.x * b.x + a.y * b.y + a.z * b.z + a.w * b.w;
}

// one wave (64 lanes) per row; lane covers 8 consecutive floats (2 x float4)
__global__ __launch_bounds__(256) void rowstats_kernel(const float* __restrict__ hg,
                                                       float* __restrict__ ws) {
    const float4* hg4     = (const float4*)hg;
    const float4* eb_sz4  = (const float4*)ws;          // 128 float4
    const float4* eb_nsz4 = (const float4*)(ws + 512);
    float* norm_o = ws + 2048;
    float* dsz_o  = ws + 2048 + NROWS;
    float* dnsz_o = ws + 2048 + 2 * NROWS;

    int wave = (blockIdx.x * blockDim.x + threadIdx.x) >> 6;  // == row
    int lane = threadIdx.x & 63;

    float4 es0 = eb_sz4[lane * 2];
    float4 es1 = eb_sz4[lane * 2 + 1];
    float4 en0 = eb_nsz4[lane * 2];
    float4 en1 = eb_nsz4[lane * 2 + 1];

    const float4* rp = hg4 + (size_t)wave * (LDIM / 4) + lane * 2;
    float4 a0 = rp[0];
    float4 a1 = rp[1];

    float ss   = dot4(a0, a0) + dot4(a1, a1);
    float dsz  = dot4(a0, es0) + dot4(a1, es1);
    float dnsz = dot4(a0, en0) + dot4(a1, en1);

#pragma unroll
    for (int off = 32; off; off >>= 1) {
        ss   += __shfl_xor(ss, off);
        dsz  += __shfl_xor(dsz, off);
        dnsz += __shfl_xor(dnsz, off);
    }
    if (lane == 0) {
        norm_o[wave] = sqrtf(ss);
        dsz_o[wave]  = dsz;
        dnsz_o[wave] = dnsz;
    }
}

// gridDim = (64, 2): 64*256 = 16384 threads per branch, branch = blockIdx.y
__global__ __launch_bounds__(256) void branch_kernel(const float* __restrict__ sim,
                                                     const int* __restrict__ sz_idx,
                                                     const int* __restrict__ nsz_idx,
                                                     const float* __restrict__ ws,
                                                     float* __restrict__ out) {
    const int b = blockIdx.y;
    const int* __restrict__ idx = (b == 0) ? sz_idx : nsz_idx;
    const unsigned mask = ((const unsigned*)ws)[1024 + b];
    const float* __restrict__ norm = ws + 2048;
    const float* __restrict__ dot  = ws + 2048 + NROWS + b * NROWS;

    const int i = blockIdx.x * blockDim.x + threadIdx.x;  // < 16384 exactly
    const int r = idx[i];

    // 20-float sim row, 80-byte aligned -> 5 x float4
    const float4* srow = (const float4*)(sim + (size_t)r * NCON);
    float4 v0 = srow[0], v1 = srow[1], v2 = srow[2], v3 = srow[3], v4 = srow[4];
    float s[NCON] = {v0.x, v0.y, v0.z, v0.w, v1.x, v1.y, v1.z, v1.w,
                     v2.x, v2.y, v2.z, v2.w, v3.x, v3.y, v3.z, v3.w,
                     v4.x, v4.y, v4.z, v4.w};

    const float invT = 1.0f / TEMP_F;
    float den = 0.f;
#pragma unroll
    for (int j = 0; j < NCON; ++j)
        if (mask & (1u << j)) den += expf(s[j] * invT);

    float term = logf(den) - dot[r] * invT / fmaxf(norm[r], 1e-12f);

    // block reduction: wave shuffle then LDS across 4 waves
    __shared__ float red[4];
#pragma unroll
    for (int off = 32; off; off >>= 1) term += __shfl_xor(term, off);
    int lane = threadIdx.x & 63;
    int w = threadIdx.x >> 6;
    if (lane == 0) red[w] = term;
    __syncthreads();
    if (threadIdx.x == 0) {
        float bsum = red[0] + red[1] + red[2] + red[3];
        atomicAdd(out, bsum * (1.0f / NSEL));
    }
}

extern "C" void kernel_launch(void* const* d_in, const int* in_sizes, int n_in,
                              void* d_out, int out_size, void* d_ws, size_t ws_size,
                              hipStream_t stream) {
    const float* hg       = (const float*)d_in[0];
    const float* hg_corr  = (const float*)d_in[1];
    const float* all_emb  = (const float*)d_in[2];
    const int*   sz_idx   = (const int*)d_in[3];
    const int*   nsz_idx  = (const int*)d_in[4];
    const int*   Psz      = (const int*)d_in[5];
    const int*   Pnsz     = (const int*)d_in[6];
    float* out = (float*)d_out;
    float* ws  = (float*)d_ws;

    prep_kernel<<<1, 512, 0, stream>>>(all_emb, Psz, Pnsz, ws, out);
    // 32768 rows, 1 wave/row, 4 waves/block -> 8192 blocks
    rowstats_kernel<<<8192, 256, 0, stream>>>(hg, ws);
    dim3 g(64, 2);
    branch_kernel<<<g, 256, 0, stream>>>(hg_corr, sz_idx, nsz_idx, ws, out);
}